// Round 17
// baseline (61.269 us; speedup 1.0000x reference)
//
#include <hip/hip_runtime.h>
#include <hip/hip_bf16.h>
#include <cstdint>

typedef __bf16 bf16x8 __attribute__((ext_vector_type(8)));
typedef float  f32x4  __attribute__((ext_vector_type(4)));
typedef unsigned short ushort8v __attribute__((ext_vector_type(8)));

constexpr int RTOT  = 2304;          // 9 taps * 256 channels, r = k*256 + c
constexpr int NITER = 36;            // BK = 64 total; 18 per split-K block
constexpr int OUTN  = 4 * 256 * 64 * 64;   // 4,194,304 floats

#define WAITV8    asm volatile("s_waitcnt vmcnt(8)" ::: "memory")
#define WAITV4    asm volatile("s_waitcnt vmcnt(4)" ::: "memory")
#define WAITV0    asm volatile("s_waitcnt vmcnt(0)" ::: "memory")
#define WAITLGKM0 asm volatile("s_waitcnt lgkmcnt(0)" ::: "memory")
#define SCHEDB    __builtin_amdgcn_sched_barrier(0)

__device__ __forceinline__ float c2f(unsigned w, int hi) {
    union { unsigned u; float f; } v;
    v.u = hi ? (w & 0xffff0000u) : (w << 16);
    return v.f;
}

// ---- merged prep: one launch does BOTH transforms ----
__global__ __launch_bounds__(256)
void prep_merged(const float* __restrict__ x, __bf16* __restrict__ xh,
                 const float* __restrict__ w, __bf16* __restrict__ wq) {
    __shared__ unsigned short tile[256][70];
    const int tid = threadIdx.x;
    if (blockIdx.x < 256) {
        const int b = blockIdx.x >> 6;
        const int y = blockIdx.x & 63;
        const float* xp = x + (size_t)b * (256 * 4096) + y * 64;
        #pragma unroll 4
        for (int it = 0; it < 64; ++it) {
            const int ci = it * 4 + (tid >> 6);
            const int xi = tid & 63;
            __bf16 h = (__bf16)xp[(size_t)ci * 4096 + xi];
            tile[ci][xi] = *reinterpret_cast<unsigned short*>(&h);
        }
        __syncthreads();
        unsigned short* op = reinterpret_cast<unsigned short*>(xh) + ((size_t)b * 64 + y) * 64 * 256;
        #pragma unroll 4
        for (int it = 0; it < 64; ++it)
            op[(size_t)it * 256 + tid] = tile[tid][it];
    } else {
        const int e = (blockIdx.x - 256) * 256 + tid;   // 73728 fragment-lanes
        const int l  = e & 63;
        const int f  = (e >> 6) & 3;
        const int wv = (e >> 8) & 7;
        const int i8 = e >> 11;
        const int nf = f & 1, half = f >> 1;
        const int co = wv * 32 + nf * 16 + (l & 15);
        const int rb = i8 * 64 + half * 32 + ((l >> 4) << 3);
        union { ushort4 u2[2]; __bf16 h[8]; } pk;
        #pragma unroll
        for (int j = 0; j < 8; ++j) {
            const int r = rb + j;
            const int c = r & 255, k = r >> 8;
            pk.h[j] = (__bf16)w[co * 2304 + c * 9 + k];
        }
        unsigned short* dst = reinterpret_cast<unsigned short*>(wq) + (size_t)e * 8;
        *reinterpret_cast<ushort4*>(dst)     = pk.u2[0];
        *reinterpret_cast<ushort4*>(dst + 4) = pk.u2[1];
    }
}

// ---- main: R13 structure, SPLIT-K x2 ----
// Block (b, ho, kb) runs iterations [kb*18, kb*18+18) of the BK=64 reduction.
// Grid = 512 -> 2 co-resident blocks/CU in INDEPENDENT barrier domains; work is
// fully partitioned (A-gathers and B-loads disjoint across kb) -- zero duplication.
// Each block writes a full-size partial; a separate reduce kernel sums them.
__global__ __launch_bounds__(512, 2)
void deform_gemm_nhwc(const float* __restrict__ off, const __bf16* __restrict__ xh,
                      const __bf16* __restrict__ wq, float* __restrict__ pbase) {
    __shared__ float4 s_w[64 * 9];
    __shared__ int4   s_a[64 * 9];
    __shared__ unsigned short sA[2][64 * 64];    // [buf][p*64 + ch], XOR-swizzled

    const int tid  = threadIdx.x;
    const int lane = tid & 63;
    const int wv   = tid >> 6;               // 0..7 = N-eighth
    const int fr   = lane & 15;
    const int fq   = lane >> 4;

    const int bs = ((blockIdx.x & 7) << 6) | (blockIdx.x >> 3);  // bijective XCD swizzle
    const int kb = bs & 1;                   // split-K half
    const int ho = (bs >> 1) & 63;
    const int b  = bs >> 7;
    const int i0 = kb * 18;

    // ---- per-(k, p) bilinear metadata (all 9 taps; both halves overlap tap 4) ----
    for (int i = tid; i < 576; i += 512) {
        const int k = i >> 6, p = i & 63;
        const int kh = k / 3, kw = k - kh * 3;
        const float dy = off[(((b * 18) + 2 * k    ) * 64 + ho) * 64 + p];
        const float dx = off[(((b * 18) + 2 * k + 1) * 64 + ho) * 64 + p];
        const float sy = (float)(ho - 1 + kh) + dy;
        const float sx = (float)(p  - 1 + kw) + dx;
        const float y0f = floorf(sy), x0f = floorf(sx);
        const float fy = sy - y0f, fx = sx - x0f;
        const int y0 = (int)y0f, x0 = (int)x0f;
        const int y1 = y0 + 1, x1 = x0 + 1;
        const bool vy0 = (unsigned)y0 < 64u, vy1 = (unsigned)y1 < 64u;
        const bool vx0 = (unsigned)x0 < 64u, vx1 = (unsigned)x1 < 64u;
        const int y0c = min(max(y0, 0), 63), y1c = min(max(y1, 0), 63);
        const int x0c = min(max(x0, 0), 63), x1c = min(max(x1, 0), 63);
        float4 wt;
        wt.x = (1.f - fy) * (1.f - fx) * ((vy0 & vx0) ? 1.f : 0.f);
        wt.y = (1.f - fy) * fx         * ((vy0 & vx1) ? 1.f : 0.f);
        wt.z = fy * (1.f - fx)         * ((vy1 & vx0) ? 1.f : 0.f);
        wt.w = fy * fx                 * ((vy1 & vx1) ? 1.f : 0.f);
        s_w[i] = wt;
        s_a[i] = make_int4((y0c << 6) + x0c, (y0c << 6) + x1c,
                           (y1c << 6) + x0c, (y1c << 6) + x1c);
    }

    f32x4 acc[4][2];
    #pragma unroll
    for (int mf = 0; mf < 4; ++mf)
        #pragma unroll
        for (int nf = 0; nf < 2; ++nf)
            acc[mf][nf] = (f32x4){0.f, 0.f, 0.f, 0.f};

    const __bf16* xb = xh + ((size_t)b << 20);
    // A-gen: 512 threads = 64 positions x 8 channel-octets (8 ch / thread / iter)
    const int p   = tid >> 3;
    const int oct = tid & 7;
    const int aw_off = (p << 6) + ((oct ^ (p & 7)) << 3);
    const char* base_lane = (const char*)xb + (oct << 4);

    // B fragment source for this wave (unique per wv; indexed by ABSOLUTE iter)
    const char* wqw = (const char*)wq + ((size_t)wv << 12) + (lane << 4);

    const int ua0 = ((0 + fq) ^ (fr & 7)) << 3;
    const int ua1 = ((4 + fq) ^ (fr & 7)) << 3;

    __syncthreads();  // meta ready

    float4 wt_k;
    uint4 ga0, ga1, ga2, ga3;
    const char *aK0, *aK1, *aK2, *aK3;
    bf16x8 br[2][4];

    {   // first tap of this half (i0>>2): kb=0 -> tap0, kb=1 -> tap4
        const int k0 = i0 >> 2;
        wt_k = s_w[(k0 << 6) + p];
        const int4 sa = s_a[(k0 << 6) + p];
        aK0 = base_lane + ((size_t)sa.x << 9);
        aK1 = base_lane + ((size_t)sa.y << 9);
        aK2 = base_lane + ((size_t)sa.z << 9);
        aK3 = base_lane + ((size_t)sa.w << 9);
    }

    // ---- prologue: load B(i0); gather+combine A(i0); issue A(i0+1) ----
    {
        const char* bb0 = wqw + (size_t)i0 * 32768;
        #pragma unroll
        for (int f = 0; f < 4; ++f)
            br[0][f] = *reinterpret_cast<const bf16x8*>(bb0 + f * 1024);
        const int cb0 = (i0 & 3) << 7;
        ga0 = *reinterpret_cast<const uint4*>(aK0 + cb0);
        ga1 = *reinterpret_cast<const uint4*>(aK1 + cb0);
        ga2 = *reinterpret_cast<const uint4*>(aK2 + cb0);
        ga3 = *reinterpret_cast<const uint4*>(aK3 + cb0);
        WAITV0;
        {
            const unsigned* w0 = reinterpret_cast<const unsigned*>(&ga0);
            const unsigned* w1 = reinterpret_cast<const unsigned*>(&ga1);
            const unsigned* w2 = reinterpret_cast<const unsigned*>(&ga2);
            const unsigned* w3 = reinterpret_cast<const unsigned*>(&ga3);
            union { ushort8v u; __bf16 h[8]; } pk;
            #pragma unroll
            for (int j = 0; j < 8; ++j)
                pk.h[j] = (__bf16)(wt_k.x * c2f(w0[j >> 1], j & 1) + wt_k.y * c2f(w1[j >> 1], j & 1)
                                 + wt_k.z * c2f(w2[j >> 1], j & 1) + wt_k.w * c2f(w3[j >> 1], j & 1));
            *reinterpret_cast<ushort8v*>(&sA[0][aw_off]) = pk.u;
        }
        // issue A(i0+1): same tap for both kb (1>>2==0, 19>>2==4)
        const int cb1 = ((i0 + 1) & 3) << 7;
        ga0 = *reinterpret_cast<const uint4*>(aK0 + cb1);
        ga1 = *reinterpret_cast<const uint4*>(aK1 + cb1);
        ga2 = *reinterpret_cast<const uint4*>(aK2 + cb1);
        ga3 = *reinterpret_cast<const uint4*>(aK3 + cb1);
        SCHEDB;
        WAITLGKM0;
        __builtin_amdgcn_s_barrier();
        SCHEDB;
    }

    // ---- main loop: 18 iterations of BK=64 (absolute iter i = i0 + ii) ----
    #pragma unroll 2
    for (int ii = 0; ii < 18; ++ii) {
        const int i = i0 + ii;
        const unsigned short* sAc = sA[ii & 1];

        // 1) A fragment reads (8 x ds_read_b128)
        bf16x8 a0[4], a1[4];
        #pragma unroll
        for (int mf = 0; mf < 4; ++mf) {
            const int ar = mf * 16 + fr;
            a0[mf] = *reinterpret_cast<const bf16x8*>(&sAc[(ar << 6) + ua0]);
            a1[mf] = *reinterpret_cast<const bf16x8*>(&sAc[(ar << 6) + ua1]);
        }

        // 2) B(i+1) reg loads (4 x dwordx4, L2-resident, unique per wave+kb)
        if (ii < 17) {
            const char* bb = wqw + (size_t)(i + 1) * 32768;
            #pragma unroll
            for (int f = 0; f < 4; ++f)
                br[(ii + 1) & 1][f] = *reinterpret_cast<const bf16x8*>(bb + f * 1024);
        }
        SCHEDB;

        // 3) drain B(i) (1 iter old), keep A(i+1)+B(i+1); MFMA K-half 0
        if (ii == 17) { WAITV0; } else { WAITV8; }
        __builtin_amdgcn_s_setprio(1);
        #pragma unroll
        for (int mf = 0; mf < 4; ++mf)
            #pragma unroll
            for (int nf = 0; nf < 2; ++nf)
                acc[mf][nf] = __builtin_amdgcn_mfma_f32_16x16x32_bf16(a0[mf], br[ii & 1][nf], acc[mf][nf], 0, 0, 0);
        __builtin_amdgcn_s_setprio(0);
        SCHEDB;

        // 4) combine A(i+1): drain gathers (1 iter old), keep B(i+1); write sA
        if (ii < 17) {
            WAITV4;
            unsigned short* sAn = const_cast<unsigned short*>(sA[(ii + 1) & 1]);
            const unsigned* w0 = reinterpret_cast<const unsigned*>(&ga0);
            const unsigned* w1 = reinterpret_cast<const unsigned*>(&ga1);
            const unsigned* w2 = reinterpret_cast<const unsigned*>(&ga2);
            const unsigned* w3 = reinterpret_cast<const unsigned*>(&ga3);
            union { ushort8v u; __bf16 h[8]; } pk;
            #pragma unroll
            for (int j = 0; j < 8; ++j)
                pk.h[j] = (__bf16)(wt_k.x * c2f(w0[j >> 1], j & 1) + wt_k.y * c2f(w1[j >> 1], j & 1)
                                 + wt_k.z * c2f(w2[j >> 1], j & 1) + wt_k.w * c2f(w3[j >> 1], j & 1));
            *reinterpret_cast<ushort8v*>(&sAn[aw_off]) = pk.u;
        }
        SCHEDB;

        // 5) issue A(i+2) gathers; tap meta reload when (i+2)%4 == 0
        if (ii < 16) {
            const int ia = i + 2;
            if ((ia & 3) == 0) {
                const int kk = ia >> 2;
                wt_k = s_w[(kk << 6) + p];
                const int4 sa = s_a[(kk << 6) + p];
                aK0 = base_lane + ((size_t)sa.x << 9);
                aK1 = base_lane + ((size_t)sa.y << 9);
                aK2 = base_lane + ((size_t)sa.z << 9);
                aK3 = base_lane + ((size_t)sa.w << 9);
            }
            const int cb = (ia & 3) << 7;
            ga0 = *reinterpret_cast<const uint4*>(aK0 + cb);
            ga1 = *reinterpret_cast<const uint4*>(aK1 + cb);
            ga2 = *reinterpret_cast<const uint4*>(aK2 + cb);
            ga3 = *reinterpret_cast<const uint4*>(aK3 + cb);
        }
        SCHEDB;

        // 6) MFMA K-half 1
        __builtin_amdgcn_s_setprio(1);
        #pragma unroll
        for (int mf = 0; mf < 4; ++mf)
            #pragma unroll
            for (int nf = 0; nf < 2; ++nf)
                acc[mf][nf] = __builtin_amdgcn_mfma_f32_16x16x32_bf16(a1[mf], br[ii & 1][2 + nf], acc[mf][nf], 0, 0, 0);
        __builtin_amdgcn_s_setprio(0);

        // 7) pre-barrier: drain only ds ops; younger VMEM crosses the barrier
        WAITLGKM0;
        __builtin_amdgcn_s_barrier();
        SCHEDB;
    }

    // ---- epilogue: write this half's partial ----
    float* ob = pbase + (size_t)kb * OUTN + (size_t)b * (256 * 4096) + (ho << 6);
    #pragma unroll
    for (int nf = 0; nf < 2; ++nf) {
        const int n = (wv << 5) + nf * 16 + fr;
        #pragma unroll
        for (int mf = 0; mf < 4; ++mf) {
            const int m = mf * 16 + (fq << 2);
            *reinterpret_cast<f32x4*>(&ob[(size_t)n * 4096 + m]) = acc[mf][nf];
        }
    }
}

// ---- reduce: out = p0 + p1 (exact 2-way sum, order-independent) ----
__global__ __launch_bounds__(256)
void reduce_add(const float* __restrict__ pb, float* __restrict__ out) {
    const size_t i = ((size_t)blockIdx.x * 256 + threadIdx.x) * 8;
    const f32x4 a0 = *reinterpret_cast<const f32x4*>(pb + i);
    const f32x4 a1 = *reinterpret_cast<const f32x4*>(pb + i + 4);
    const f32x4 b0 = *reinterpret_cast<const f32x4*>(pb + OUTN + i);
    const f32x4 b1 = *reinterpret_cast<const f32x4*>(pb + OUTN + i + 4);
    *reinterpret_cast<f32x4*>(out + i)     = a0 + b0;
    *reinterpret_cast<f32x4*>(out + i + 4) = a1 + b1;
}

// ---- fallback (ws too small): convert-on-the-fly weights, NCHW gathers ----
__global__ __launch_bounds__(256, 2)
void deform_gemm_fb(const float* __restrict__ x, const float* __restrict__ off,
                    const float* __restrict__ wf, float* __restrict__ out) {
    __shared__ float4 s_w[32 * 9];
    __shared__ int4   s_a[32 * 9];
    __shared__ unsigned short sA[2][32 * 32];
    __shared__ unsigned short sB[2][256 * 32];

    const int tid  = threadIdx.x;
    const int lane = tid & 63;
    const int wv   = tid >> 6;
    const int fr   = lane & 15;
    const int fq   = lane >> 4;
    const int bs  = ((blockIdx.x & 7) << 6) | (blockIdx.x >> 3);
    const int b   = bs >> 7;
    const int ho  = (bs >> 1) & 63;
    const int wo0 = (bs & 1) << 5;

    for (int i = tid; i < 32 * 9; i += 256) {
        const int k = i >> 5, p = i & 31, wo = wo0 + p;
        const int kh = k / 3, kw = k - kh * 3;
        const float dy = off[(((b * 18) + 2 * k    ) * 64 + ho) * 64 + wo];
        const float dx = off[(((b * 18) + 2 * k + 1) * 64 + ho) * 64 + wo];
        const float sy = (float)(ho - 1 + kh) + dy;
        const float sx = (float)(wo - 1 + kw) + dx;
        const float y0f = floorf(sy), x0f = floorf(sx);
        const float fy = sy - y0f, fx = sx - x0f;
        const int y0 = (int)y0f, x0 = (int)x0f;
        const int y1 = y0 + 1, x1 = x0 + 1;
        const bool vy0 = (unsigned)y0 < 64u, vy1 = (unsigned)y1 < 64u;
        const bool vx0 = (unsigned)x0 < 64u, vx1 = (unsigned)x1 < 64u;
        const int y0c = min(max(y0, 0), 63), y1c = min(max(y1, 0), 63);
        const int x0c = min(max(x0, 0), 63), x1c = min(max(x1, 0), 63);
        float4 wt;
        wt.x = (1.f - fy) * (1.f - fx) * ((vy0 & vx0) ? 1.f : 0.f);
        wt.y = (1.f - fy) * fx         * ((vy0 & vx1) ? 1.f : 0.f);
        wt.z = fy * (1.f - fx)         * ((vy1 & vx0) ? 1.f : 0.f);
        wt.w = fy * fx                 * ((vy1 & vx1) ? 1.f : 0.f);
        s_w[i] = wt;
        s_a[i] = make_int4((y0c << 6) + x0c, (y0c << 6) + x1c,
                           (y1c << 6) + x0c, (y1c << 6) + x1c);
    }

    f32x4 acc[2][4];
    #pragma unroll
    for (int mf = 0; mf < 2; ++mf)
        #pragma unroll
        for (int nf = 0; nf < 4; ++nf)
            acc[mf][nf] = (f32x4){0.f, 0.f, 0.f, 0.f};

    const float* xb = x + (size_t)b * (256 * 4096);
    const int p  = tid & 31;
    const int rq = tid >> 5;
    const int aw_off = (p << 5) + ((((rq >> 1) ^ ((p >> 1) & 3)) << 3)) + ((rq & 1) << 2);

    int brow[4], bcol[4];
    #pragma unroll
    for (int q = 0; q < 4; ++q) {
        brow[q] = (wv << 6) + (q << 4) + (lane >> 2);
        bcol[q] = ((lane & 3) ^ ((brow[q] >> 1) & 3)) << 3;
    }
    const int bphys = (lane & 3) << 3;

    __syncthreads();

    for (int t = 0; t < 72; ++t) {
        const int cur = t & 1;
        const int r0 = t * 32;
        union { ushort4 u; __bf16 h[4]; } pk;
        #pragma unroll
        for (int j = 0; j < 4; ++j) {
            const int r = r0 + rq * 4 + j;
            const int c = r / 9, k = r - c * 9;
            const float4 wt = s_w[(k << 5) + p];
            const int4 ad = s_a[(k << 5) + p];
            const float* xp = xb + (c << 12);
            pk.h[j] = (__bf16)(wt.x * xp[ad.x] + wt.y * xp[ad.y]
                             + wt.z * xp[ad.z] + wt.w * xp[ad.w]);
        }
        *reinterpret_cast<ushort4*>(&sA[cur][aw_off]) = pk.u;
        #pragma unroll
        for (int q = 0; q < 4; ++q) {
            const float4* s = reinterpret_cast<const float4*>(wf + (size_t)brow[q] * RTOT + r0 + bcol[q]);
            float4 f0 = s[0], f1 = s[1];
            union { uint4 u; __bf16 h[8]; } ub;
            ub.h[0]=(__bf16)f0.x; ub.h[1]=(__bf16)f0.y; ub.h[2]=(__bf16)f0.z; ub.h[3]=(__bf16)f0.w;
            ub.h[4]=(__bf16)f1.x; ub.h[5]=(__bf16)f1.y; ub.h[6]=(__bf16)f1.z; ub.h[7]=(__bf16)f1.w;
            *reinterpret_cast<uint4*>(&sB[cur][(brow[q] << 5) + bphys]) = ub.u;
        }
        __syncthreads();
        bf16x8 af[2], bfr[4];
        #pragma unroll
        for (int mf = 0; mf < 2; ++mf) {
            const int row = mf * 16 + fr;
            af[mf] = *reinterpret_cast<const bf16x8*>(&sA[cur][(row << 5) + ((fq ^ ((row >> 1) & 3)) << 3)]);
        }
        #pragma unroll
        for (int nf = 0; nf < 4; ++nf) {
            const int row = (wv << 6) + nf * 16 + fr;
            bfr[nf] = *reinterpret_cast<const bf16x8*>(&sB[cur][(row << 5) + ((fq ^ ((row >> 1) & 3)) << 3)]);
        }
        #pragma unroll
        for (int mf = 0; mf < 2; ++mf)
            #pragma unroll
            for (int nf = 0; nf < 4; ++nf)
                acc[mf][nf] = __builtin_amdgcn_mfma_f32_16x16x32_bf16(af[mf], bfr[nf], acc[mf][nf], 0, 0, 0);
        __syncthreads();
    }

    float* ob = out + (size_t)b * (256 * 4096) + (ho << 6) + wo0;
    #pragma unroll
    for (int nf = 0; nf < 4; ++nf) {
        const int n = (wv << 6) + nf * 16 + fr;
        #pragma unroll
        for (int mf = 0; mf < 2; ++mf) {
            const int m = mf * 16 + (fq << 2);
            *reinterpret_cast<f32x4*>(&ob[(size_t)n * 4096 + m]) = acc[mf][nf];
        }
    }
}

extern "C" void kernel_launch(void* const* d_in, const int* in_sizes, int n_in,
                              void* d_out, int out_size, void* d_ws, size_t ws_size,
                              hipStream_t stream) {
    const float* x   = (const float*)d_in[0];
    const float* off = (const float*)d_in[1];
    const float* w   = (const float*)d_in[2];
    float* out = (float*)d_out;

    const size_t xh_bytes = (size_t)4 * 64 * 64 * 256 * sizeof(__bf16);   // 8.4 MB
    const size_t wq_bytes = (size_t)NITER * 8 * 4 * 64 * 16;              // 1.18 MB
    const size_t pp_bytes = (size_t)2 * OUTN * sizeof(float);             // 33.6 MB
    if (ws_size >= xh_bytes + wq_bytes + pp_bytes) {
        __bf16* xh = (__bf16*)d_ws;
        __bf16* wq = (__bf16*)((char*)d_ws + xh_bytes);
        float*  pb = (float*)((char*)d_ws + xh_bytes + wq_bytes);
        prep_merged<<<dim3(544), dim3(256), 0, stream>>>(x, xh, w, wq);
        deform_gemm_nhwc<<<dim3(512), dim3(512), 0, stream>>>(off, xh, wq, pb);
        reduce_add<<<dim3(2048), dim3(256), 0, stream>>>(pb, out);
    } else {
        deform_gemm_fb<<<dim3(512), dim3(256), 0, stream>>>(x, off, w, out);
    }
}

// Round 18
// 47.437 us; speedup vs baseline: 1.2916x; 1.2916x over previous
//
#include <hip/hip_runtime.h>
#include <hip/hip_bf16.h>
#include <cstdint>

typedef __bf16 bf16x8 __attribute__((ext_vector_type(8)));
typedef float  f32x4  __attribute__((ext_vector_type(4)));
typedef unsigned short ushort8v __attribute__((ext_vector_type(8)));

constexpr int RTOT  = 2304;          // 9 taps * 256 channels, r = k*256 + c
constexpr int NITER = 36;            // BK = 64 per iteration

#define WAITV8    asm volatile("s_waitcnt vmcnt(8)" ::: "memory")
#define WAITV4    asm volatile("s_waitcnt vmcnt(4)" ::: "memory")
#define WAITV0    asm volatile("s_waitcnt vmcnt(0)" ::: "memory")
#define WAITLGKM0 asm volatile("s_waitcnt lgkmcnt(0)" ::: "memory")
#define SCHEDB    __builtin_amdgcn_sched_barrier(0)

__device__ __forceinline__ float c2f(unsigned w, int hi) {
    union { unsigned u; float f; } v;
    v.u = hi ? (w & 0xffff0000u) : (w << 16);
    return v.f;
}

// ---- merged prep: one launch does BOTH transforms ----
// Blocks [0, 256):   x [4,256,64,64] f32 (NCHW) -> xh [4,64,64,256] bf16 (NHWC)
// Blocks [256, 544): w [co][c][k] f32 -> wq, per-lane MFMA B fragments.
__global__ __launch_bounds__(256)
void prep_merged(const float* __restrict__ x, __bf16* __restrict__ xh,
                 const float* __restrict__ w, __bf16* __restrict__ wq) {
    __shared__ unsigned short tile[256][70];
    const int tid = threadIdx.x;
    if (blockIdx.x < 256) {
        const int b = blockIdx.x >> 6;
        const int y = blockIdx.x & 63;
        const float* xp = x + (size_t)b * (256 * 4096) + y * 64;
        #pragma unroll 4
        for (int it = 0; it < 64; ++it) {
            const int ci = it * 4 + (tid >> 6);
            const int xi = tid & 63;
            __bf16 h = (__bf16)xp[(size_t)ci * 4096 + xi];
            tile[ci][xi] = *reinterpret_cast<unsigned short*>(&h);
        }
        __syncthreads();
        unsigned short* op = reinterpret_cast<unsigned short*>(xh) + ((size_t)b * 64 + y) * 64 * 256;
        #pragma unroll 4
        for (int it = 0; it < 64; ++it)
            op[(size_t)it * 256 + tid] = tile[tid][it];
    } else {
        const int e = (blockIdx.x - 256) * 256 + tid;   // 73728 fragment-lanes
        const int l  = e & 63;
        const int f  = (e >> 6) & 3;
        const int wv = (e >> 8) & 7;
        const int i8 = e >> 11;
        const int nf = f & 1, half = f >> 1;
        const int co = wv * 32 + nf * 16 + (l & 15);
        const int rb = i8 * 64 + half * 32 + ((l >> 4) << 3);
        union { ushort4 u2[2]; __bf16 h[8]; } pk;
        #pragma unroll
        for (int j = 0; j < 8; ++j) {
            const int r = rb + j;
            const int c = r & 255, k = r >> 8;
            pk.h[j] = (__bf16)w[co * 2304 + c * 9 + k];
        }
        unsigned short* dst = reinterpret_cast<unsigned short*>(wq) + (size_t)e * 8;
        *reinterpret_cast<ushort4*>(dst)     = pk.u2[0];
        *reinterpret_cast<ushort4*>(dst + 4) = pk.u2[1];
    }
}

// ---- main: fused deformable implicit GEMM, BK=64, A-only LDS, B L2->reg ----
// (round-13 structure: best-measured configuration, ~44.5 us kernel)
__global__ __launch_bounds__(512, 1)
void deform_gemm_nhwc(const float* __restrict__ off, const __bf16* __restrict__ xh,
                      const __bf16* __restrict__ wq, float* __restrict__ out) {
    __shared__ float4 s_w[64 * 9];
    __shared__ int4   s_a[64 * 9];
    __shared__ unsigned short sA[2][64 * 64];    // [buf][p*64 + ch], XOR-swizzled

    const int tid  = threadIdx.x;
    const int lane = tid & 63;
    const int wv   = tid >> 6;               // 0..7 = N-eighth
    const int fr   = lane & 15;
    const int fq   = lane >> 4;

    const int bs = ((blockIdx.x & 7) << 5) | (blockIdx.x >> 3);  // bijective XCD swizzle
    const int b  = bs >> 6;
    const int ho = bs & 63;

    // ---- per-(k, p) bilinear metadata (9 taps x 64 positions) ----
    for (int i = tid; i < 576; i += 512) {
        const int k = i >> 6, p = i & 63;
        const int kh = k / 3, kw = k - kh * 3;
        const float dy = off[(((b * 18) + 2 * k    ) * 64 + ho) * 64 + p];
        const float dx = off[(((b * 18) + 2 * k + 1) * 64 + ho) * 64 + p];
        const float sy = (float)(ho - 1 + kh) + dy;
        const float sx = (float)(p  - 1 + kw) + dx;
        const float y0f = floorf(sy), x0f = floorf(sx);
        const float fy = sy - y0f, fx = sx - x0f;
        const int y0 = (int)y0f, x0 = (int)x0f;
        const int y1 = y0 + 1, x1 = x0 + 1;
        const bool vy0 = (unsigned)y0 < 64u, vy1 = (unsigned)y1 < 64u;
        const bool vx0 = (unsigned)x0 < 64u, vx1 = (unsigned)x1 < 64u;
        const int y0c = min(max(y0, 0), 63), y1c = min(max(y1, 0), 63);
        const int x0c = min(max(x0, 0), 63), x1c = min(max(x1, 0), 63);
        float4 wt;
        wt.x = (1.f - fy) * (1.f - fx) * ((vy0 & vx0) ? 1.f : 0.f);
        wt.y = (1.f - fy) * fx         * ((vy0 & vx1) ? 1.f : 0.f);
        wt.z = fy * (1.f - fx)         * ((vy1 & vx0) ? 1.f : 0.f);
        wt.w = fy * fx                 * ((vy1 & vx1) ? 1.f : 0.f);
        s_w[i] = wt;
        s_a[i] = make_int4((y0c << 6) + x0c, (y0c << 6) + x1c,
                           (y1c << 6) + x0c, (y1c << 6) + x1c);
    }

    f32x4 acc[4][2];
    #pragma unroll
    for (int mf = 0; mf < 4; ++mf)
        #pragma unroll
        for (int nf = 0; nf < 2; ++nf)
            acc[mf][nf] = (f32x4){0.f, 0.f, 0.f, 0.f};

    const __bf16* xb = xh + ((size_t)b << 20);
    const int p   = tid >> 3;                // 0..63
    const int oct = tid & 7;                 // c = oct*8 within the 64-ch iter block
    const int aw_off = (p << 6) + ((oct ^ (p & 7)) << 3);
    const char* base_lane = (const char*)xb + (oct << 4);

    const char* wqw = (const char*)wq + ((size_t)wv << 12) + (lane << 4);

    const int ua0 = ((0 + fq) ^ (fr & 7)) << 3;
    const int ua1 = ((4 + fq) ^ (fr & 7)) << 3;

    __syncthreads();  // meta ready

    float4 wt_k;
    uint4 ga0, ga1, ga2, ga3;
    const char *aK0, *aK1, *aK2, *aK3;
    bf16x8 br[2][4];

    {   // tap 0 meta
        wt_k = s_w[p];
        const int4 sa = s_a[p];
        aK0 = base_lane + ((size_t)sa.x << 9);
        aK1 = base_lane + ((size_t)sa.y << 9);
        aK2 = base_lane + ((size_t)sa.z << 9);
        aK3 = base_lane + ((size_t)sa.w << 9);
    }

    // ---- prologue: load B(0); gather+combine A(0); issue A(1) ----
    {
        #pragma unroll
        for (int f = 0; f < 4; ++f)
            br[0][f] = *reinterpret_cast<const bf16x8*>(wqw + f * 1024);
        ga0 = *reinterpret_cast<const uint4*>(aK0);
        ga1 = *reinterpret_cast<const uint4*>(aK1);
        ga2 = *reinterpret_cast<const uint4*>(aK2);
        ga3 = *reinterpret_cast<const uint4*>(aK3);
        WAITV0;
        {
            const unsigned* w0 = reinterpret_cast<const unsigned*>(&ga0);
            const unsigned* w1 = reinterpret_cast<const unsigned*>(&ga1);
            const unsigned* w2 = reinterpret_cast<const unsigned*>(&ga2);
            const unsigned* w3 = reinterpret_cast<const unsigned*>(&ga3);
            union { ushort8v u; __bf16 h[8]; } pk;
            #pragma unroll
            for (int j = 0; j < 8; ++j)
                pk.h[j] = (__bf16)(wt_k.x * c2f(w0[j >> 1], j & 1) + wt_k.y * c2f(w1[j >> 1], j & 1)
                                 + wt_k.z * c2f(w2[j >> 1], j & 1) + wt_k.w * c2f(w3[j >> 1], j & 1));
            *reinterpret_cast<ushort8v*>(&sA[0][aw_off]) = pk.u;
        }
        ga0 = *reinterpret_cast<const uint4*>(aK0 + 128);
        ga1 = *reinterpret_cast<const uint4*>(aK1 + 128);
        ga2 = *reinterpret_cast<const uint4*>(aK2 + 128);
        ga3 = *reinterpret_cast<const uint4*>(aK3 + 128);
        SCHEDB;
        WAITLGKM0;
        __builtin_amdgcn_s_barrier();
        SCHEDB;
    }

    // ---- main loop: 36 iterations of BK=64 ----
    #pragma unroll 4
    for (int i = 0; i < NITER; ++i) {
        const unsigned short* sAc = sA[i & 1];

        // 1) A fragment reads (8 x ds_read_b128)
        bf16x8 a0[4], a1[4];
        #pragma unroll
        for (int mf = 0; mf < 4; ++mf) {
            const int ar = mf * 16 + fr;
            a0[mf] = *reinterpret_cast<const bf16x8*>(&sAc[(ar << 6) + ua0]);
            a1[mf] = *reinterpret_cast<const bf16x8*>(&sAc[(ar << 6) + ua1]);
        }

        // 2) B(i+1) reg loads (4 x dwordx4, coalesced, L2-resident, unique per wave)
        if (i < NITER - 1) {
            const char* bb = wqw + (size_t)(i + 1) * 32768;
            #pragma unroll
            for (int f = 0; f < 4; ++f)
                br[(i + 1) & 1][f] = *reinterpret_cast<const bf16x8*>(bb + f * 1024);
        }
        SCHEDB;

        // 3) drain B(i) (issued 1 iter ago), keep A(i+1)+B(i+1); MFMA K-half 0
        if (i == NITER - 1) { WAITV0; } else { WAITV8; }
        __builtin_amdgcn_s_setprio(1);
        #pragma unroll
        for (int mf = 0; mf < 4; ++mf)
            #pragma unroll
            for (int nf = 0; nf < 2; ++nf)
                acc[mf][nf] = __builtin_amdgcn_mfma_f32_16x16x32_bf16(a0[mf], br[i & 1][nf], acc[mf][nf], 0, 0, 0);
        __builtin_amdgcn_s_setprio(0);
        SCHEDB;

        // 4) combine A(i+1): drain A gathers (1 iter old), keep B(i+1); write sA
        if (i < NITER - 1) {
            WAITV4;
            unsigned short* sAn = const_cast<unsigned short*>(sA[(i + 1) & 1]);
            const unsigned* w0 = reinterpret_cast<const unsigned*>(&ga0);
            const unsigned* w1 = reinterpret_cast<const unsigned*>(&ga1);
            const unsigned* w2 = reinterpret_cast<const unsigned*>(&ga2);
            const unsigned* w3 = reinterpret_cast<const unsigned*>(&ga3);
            union { ushort8v u; __bf16 h[8]; } pk;
            #pragma unroll
            for (int j = 0; j < 8; ++j)
                pk.h[j] = (__bf16)(wt_k.x * c2f(w0[j >> 1], j & 1) + wt_k.y * c2f(w1[j >> 1], j & 1)
                                 + wt_k.z * c2f(w2[j >> 1], j & 1) + wt_k.w * c2f(w3[j >> 1], j & 1));
            *reinterpret_cast<ushort8v*>(&sAn[aw_off]) = pk.u;
        }
        SCHEDB;

        // 5) issue A(i+2) gathers; tap meta reload when (i+2)%4 == 0
        if (i < NITER - 2) {
            const int ia = i + 2;
            if ((ia & 3) == 0) {
                const int kk = ia >> 2;
                wt_k = s_w[(kk << 6) + p];
                const int4 sa = s_a[(kk << 6) + p];
                aK0 = base_lane + ((size_t)sa.x << 9);
                aK1 = base_lane + ((size_t)sa.y << 9);
                aK2 = base_lane + ((size_t)sa.z << 9);
                aK3 = base_lane + ((size_t)sa.w << 9);
            }
            const int cb = (ia & 3) << 7;
            ga0 = *reinterpret_cast<const uint4*>(aK0 + cb);
            ga1 = *reinterpret_cast<const uint4*>(aK1 + cb);
            ga2 = *reinterpret_cast<const uint4*>(aK2 + cb);
            ga3 = *reinterpret_cast<const uint4*>(aK3 + cb);
        }
        SCHEDB;

        // 6) MFMA K-half 1 (B(i) half1 already in regs)
        __builtin_amdgcn_s_setprio(1);
        #pragma unroll
        for (int mf = 0; mf < 4; ++mf)
            #pragma unroll
            for (int nf = 0; nf < 2; ++nf)
                acc[mf][nf] = __builtin_amdgcn_mfma_f32_16x16x32_bf16(a1[mf], br[i & 1][2 + nf], acc[mf][nf], 0, 0, 0);
        __builtin_amdgcn_s_setprio(0);

        // 7) pre-barrier: drain only ds ops; B(i+1)x4 and A(i+2)x4 cross the barrier
        WAITLGKM0;
        __builtin_amdgcn_s_barrier();
        SCHEDB;
    }

    // ---- epilogue: rows m = mf*16 + fq*4 + j, cols n = wv*32 + nf*16 + fr ----
    float* ob = out + (size_t)b * (256 * 4096) + (ho << 6);
    #pragma unroll
    for (int nf = 0; nf < 2; ++nf) {
        const int n = (wv << 5) + nf * 16 + fr;
        #pragma unroll
        for (int mf = 0; mf < 4; ++mf) {
            const int m = mf * 16 + (fq << 2);
            *reinterpret_cast<f32x4*>(&ob[(size_t)n * 4096 + m]) = acc[mf][nf];
        }
    }
}

// ---- fallback (ws too small): convert-on-the-fly weights, NCHW gathers ----
__global__ __launch_bounds__(256, 2)
void deform_gemm_fb(const float* __restrict__ x, const float* __restrict__ off,
                    const float* __restrict__ wf, float* __restrict__ out) {
    __shared__ float4 s_w[32 * 9];
    __shared__ int4   s_a[32 * 9];
    __shared__ unsigned short sA[2][32 * 32];
    __shared__ unsigned short sB[2][256 * 32];

    const int tid  = threadIdx.x;
    const int lane = tid & 63;
    const int wv   = tid >> 6;
    const int fr   = lane & 15;
    const int fq   = lane >> 4;
    const int bs  = ((blockIdx.x & 7) << 6) | (blockIdx.x >> 3);
    const int b   = bs >> 7;
    const int ho  = (bs >> 1) & 63;
    const int wo0 = (bs & 1) << 5;

    for (int i = tid; i < 32 * 9; i += 256) {
        const int k = i >> 5, p = i & 31, wo = wo0 + p;
        const int kh = k / 3, kw = k - kh * 3;
        const float dy = off[(((b * 18) + 2 * k    ) * 64 + ho) * 64 + wo];
        const float dx = off[(((b * 18) + 2 * k + 1) * 64 + ho) * 64 + wo];
        const float sy = (float)(ho - 1 + kh) + dy;
        const float sx = (float)(wo - 1 + kw) + dx;
        const float y0f = floorf(sy), x0f = floorf(sx);
        const float fy = sy - y0f, fx = sx - x0f;
        const int y0 = (int)y0f, x0 = (int)x0f;
        const int y1 = y0 + 1, x1 = x0 + 1;
        const bool vy0 = (unsigned)y0 < 64u, vy1 = (unsigned)y1 < 64u;
        const bool vx0 = (unsigned)x0 < 64u, vx1 = (unsigned)x1 < 64u;
        const int y0c = min(max(y0, 0), 63), y1c = min(max(y1, 0), 63);
        const int x0c = min(max(x0, 0), 63), x1c = min(max(x1, 0), 63);
        float4 wt;
        wt.x = (1.f - fy) * (1.f - fx) * ((vy0 & vx0) ? 1.f : 0.f);
        wt.y = (1.f - fy) * fx         * ((vy0 & vx1) ? 1.f : 0.f);
        wt.z = fy * (1.f - fx)         * ((vy1 & vx0) ? 1.f : 0.f);
        wt.w = fy * fx                 * ((vy1 & vx1) ? 1.f : 0.f);
        s_w[i] = wt;
        s_a[i] = make_int4((y0c << 6) + x0c, (y0c << 6) + x1c,
                           (y1c << 6) + x0c, (y1c << 6) + x1c);
    }

    f32x4 acc[2][4];
    #pragma unroll
    for (int mf = 0; mf < 2; ++mf)
        #pragma unroll
        for (int nf = 0; nf < 4; ++nf)
            acc[mf][nf] = (f32x4){0.f, 0.f, 0.f, 0.f};

    const float* xb = x + (size_t)b * (256 * 4096);
    const int p  = tid & 31;
    const int rq = tid >> 5;
    const int aw_off = (p << 5) + ((((rq >> 1) ^ ((p >> 1) & 3)) << 3)) + ((rq & 1) << 2);

    int brow[4], bcol[4];
    #pragma unroll
    for (int q = 0; q < 4; ++q) {
        brow[q] = (wv << 6) + (q << 4) + (lane >> 2);
        bcol[q] = ((lane & 3) ^ ((brow[q] >> 1) & 3)) << 3;
    }
    const int bphys = (lane & 3) << 3;

    __syncthreads();

    for (int t = 0; t < 72; ++t) {
        const int cur = t & 1;
        const int r0 = t * 32;
        union { ushort4 u; __bf16 h[4]; } pk;
        #pragma unroll
        for (int j = 0; j < 4; ++j) {
            const int r = r0 + rq * 4 + j;
            const int c = r / 9, k = r - c * 9;
            const float4 wt = s_w[(k << 5) + p];
            const int4 ad = s_a[(k << 5) + p];
            const float* xp = xb + (c << 12);
            pk.h[j] = (__bf16)(wt.x * xp[ad.x] + wt.y * xp[ad.y]
                             + wt.z * xp[ad.z] + wt.w * xp[ad.w]);
        }
        *reinterpret_cast<ushort4*>(&sA[cur][aw_off]) = pk.u;
        #pragma unroll
        for (int q = 0; q < 4; ++q) {
            const float4* s = reinterpret_cast<const float4*>(wf + (size_t)brow[q] * RTOT + r0 + bcol[q]);
            float4 f0 = s[0], f1 = s[1];
            union { uint4 u; __bf16 h[8]; } ub;
            ub.h[0]=(__bf16)f0.x; ub.h[1]=(__bf16)f0.y; ub.h[2]=(__bf16)f0.z; ub.h[3]=(__bf16)f0.w;
            ub.h[4]=(__bf16)f1.x; ub.h[5]=(__bf16)f1.y; ub.h[6]=(__bf16)f1.z; ub.h[7]=(__bf16)f1.w;
            *reinterpret_cast<uint4*>(&sB[cur][(brow[q] << 5) + bphys]) = ub.u;
        }
        __syncthreads();
        bf16x8 af[2], bfr[4];
        #pragma unroll
        for (int mf = 0; mf < 2; ++mf) {
            const int row = mf * 16 + fr;
            af[mf] = *reinterpret_cast<const bf16x8*>(&sA[cur][(row << 5) + ((fq ^ ((row >> 1) & 3)) << 3)]);
        }
        #pragma unroll
        for (int nf = 0; nf < 4; ++nf) {
            const int row = (wv << 6) + nf * 16 + fr;
            bfr[nf] = *reinterpret_cast<const bf16x8*>(&sB[cur][(row << 5) + ((fq ^ ((row >> 1) & 3)) << 3)]);
        }
        #pragma unroll
        for (int mf = 0; mf < 2; ++mf)
            #pragma unroll
            for (int nf = 0; nf < 4; ++nf)
                acc[mf][nf] = __builtin_amdgcn_mfma_f32_16x16x32_bf16(af[mf], bfr[nf], acc[mf][nf], 0, 0, 0);
        __syncthreads();
    }

    float* ob = out + (size_t)b * (256 * 4096) + (ho << 6) + wo0;
    #pragma unroll
    for (int nf = 0; nf < 4; ++nf) {
        const int n = (wv << 6) + nf * 16 + fr;
        #pragma unroll
        for (int mf = 0; mf < 2; ++mf) {
            const int m = mf * 16 + (fq << 2);
            *reinterpret_cast<f32x4*>(&ob[(size_t)n * 4096 + m]) = acc[mf][nf];
        }
    }
}

extern "C" void kernel_launch(void* const* d_in, const int* in_sizes, int n_in,
                              void* d_out, int out_size, void* d_ws, size_t ws_size,
                              hipStream_t stream) {
    const float* x   = (const float*)d_in[0];
    const float* off = (const float*)d_in[1];
    const float* w   = (const float*)d_in[2];
    float* out = (float*)d_out;

    const size_t xh_bytes = (size_t)4 * 64 * 64 * 256 * sizeof(__bf16);   // 8.4 MB
    const size_t wq_bytes = (size_t)NITER * 8 * 4 * 64 * 16;              // 1.18 MB
    if (ws_size >= xh_bytes + wq_bytes) {
        __bf16* xh = (__bf16*)d_ws;
        __bf16* wq = (__bf16*)((char*)d_ws + xh_bytes);
        prep_merged<<<dim3(544), dim3(256), 0, stream>>>(x, xh, w, wq);
        deform_gemm_nhwc<<<dim3(256), dim3(512), 0, stream>>>(off, xh, wq, out);
    } else {
        deform_gemm_fb<<<dim3(512), dim3(256), 0, stream>>>(x, off, w, out);
    }
}